// Round 1
// baseline (2977.379 us; speedup 1.0000x reference)
//
#include <hip/hip_runtime.h>
#include <hip/hip_bf16.h>

// SceneGraph head: conv1x1 -> PrRoIPool (exact separable) -> channel matmuls -> FC -> L2norm
// Shapes fixed per setup_inputs: B=8,C=256,H=W=32,n=16,P=7,DS=16,D1=D2=256.
// Exact decomposition: rel_feat = As[sub] + Ao[obj] + Wrf_xyz @ [xr; yr*s_imap; zr*o_imap] + brf.

#define Bimg 8
#define Cch 256
#define Himg 32
#define Wimg 32
#define HW 1024
#define Nobj 16
#define NPAIR 256
#define Pp 7
#define PQ 49
#define CREL 384
#define CCAT 640
#define KFC 12544

__device__ __forceinline__ float hat_int(float t) {
    t = fminf(1.f, fmaxf(-1.f, t));
    return (t < 0.f) ? 0.5f * (t + 1.f) * (t + 1.f) : 1.f - 0.5f * (1.f - t) * (1.f - t);
}

// ---------------- weight concat (Wc over Wr) ----------------
__global__ void catw_k(const float* __restrict__ Wc, const float* __restrict__ bc,
                       const float* __restrict__ Wr, const float* __restrict__ br,
                       float* __restrict__ Wcat, float* __restrict__ bcat) {
    int t = blockIdx.x * 256 + threadIdx.x;
    if (t < CCAT * Cch) {
        int d = t / Cch, c = t % Cch;
        Wcat[t] = (d < Cch) ? Wc[d * Cch + c] : Wr[(d - Cch) * Cch + c];
    }
    if (t < CCAT) bcat[t] = (t < Cch) ? bc[t] : br[t - Cch];
}

// ---------------- per-roi axis weights + support ranges + inv-area ----------------
// rng layout per roi (28 ints): [x_lo(7), x_hi(7), y_lo(7), y_hi(7)]
__global__ void axisw_k(const float* __restrict__ objects,
                        float* wxo, float* wyo, float* iao, int* rngo,
                        float* wxu, float* wyu, float* iau, int* rngu,
                        float* wxi, float* wyi, float* iai, int* rngi) {
    int bid = blockIdx.x;
    float b0, b1, b2, b3;
    float *wx, *wy, *ia;
    int* rng;
    if (bid < 128) {
        b0 = objects[bid * 4]; b1 = objects[bid * 4 + 1];
        b2 = objects[bid * 4 + 2]; b3 = objects[bid * 4 + 3];
        wx = wxo + bid * 224; wy = wyo + bid * 224; ia = iao + bid; rng = rngo + bid * 28;
    } else if (bid < 128 + 2048) {
        int u = bid - 128;
        int img = u >> 8, pair = u & 255, i = pair >> 4, j = pair & 15;
        const float* sb = objects + (img * 16 + i) * 4;
        const float* ob = objects + (img * 16 + j) * 4;
        b0 = fminf(sb[0], ob[0]); b1 = fminf(sb[1], ob[1]);
        b2 = fmaxf(sb[2], ob[2]); b3 = fmaxf(sb[3], ob[3]);
        wx = wxu + u * 224; wy = wyu + u * 224; ia = iau + u; rng = rngu + u * 28;
    } else {
        b0 = 0.f; b1 = 0.f; b2 = 512.f; b3 = 512.f;
        wx = wxi; wy = wyi; ia = iai; rng = rngi;
    }
    const float sc = 0.0625f;
    int tid = threadIdx.x;
    {   // x axis
        float lo = b0 * sc, hi = b2 * sc, bw = (hi - lo) * (1.f / 7.f);
        for (int e = tid; e < 224; e += 64) {
            int p = e / 32, i2 = e % 32;
            float st = lo + bw * p, en = st + bw;
            wx[e] = hat_int(en - (float)i2) - hat_int(st - (float)i2);
        }
        if (tid < 7) {
            float st = lo + bw * tid, en = st + bw;
            rng[tid] = max(0, (int)floorf(st) - 1);
            rng[7 + tid] = min(31, (int)ceilf(en) + 1);
        }
    }
    {   // y axis
        float lo = b1 * sc, hi = b3 * sc, bw = (hi - lo) * (1.f / 7.f);
        for (int e = tid; e < 224; e += 64) {
            int p = e / 32, i2 = e % 32;
            float st = lo + bw * p, en = st + bw;
            wy[e] = hat_int(en - (float)i2) - hat_int(st - (float)i2);
        }
        if (tid < 7) {
            float st = lo + bw * tid, en = st + bw;
            rng[14 + tid] = max(0, (int)floorf(st) - 1);
            rng[21 + tid] = min(31, (int)ceilf(en) + 1);
        }
    }
    if (tid == 0) {
        float bwx = (b2 - b0) * sc * (1.f / 7.f), bwy = (b3 - b1) * sc * (1.f / 7.f);
        *ia = 1.f / fmaxf(bwx * bwy, 1e-8f);
    }
}

// ---------------- intersection maps ----------------
__global__ void imap_k(const float* __restrict__ objects,
                       float* __restrict__ bimap, float* __restrict__ simap,
                       float* __restrict__ oimap) {
    int bid = blockIdx.x;
    int tid = threadIdx.x;
    if (tid >= 49) return;
    int p = tid / 7, q = tid % 7;
    if (bid < 128) {
        float a0 = objects[bid * 4], a1 = objects[bid * 4 + 1];
        float a2 = objects[bid * 4 + 2], a3 = objects[bid * 4 + 3];
        float bw = 512.f / 7.f, bh = 512.f / 7.f;
        float gx0 = bw * q, gy0 = bh * p;
        float ox = fmaxf(fminf(gx0 + bw, a2) - fmaxf(gx0, a0), 0.f);
        float oy = fmaxf(fminf(gy0 + bh, a3) - fmaxf(gy0, a1), 0.f);
        bimap[bid * 49 + tid] = oy * ox / fmaxf(bw * bh, 1e-8f);
    } else {
        int u = bid - 128;
        int img = u >> 8, pair = u & 255, i = pair >> 4, j = pair & 15;
        const float* sb = objects + (img * 16 + i) * 4;
        const float* ob = objects + (img * 16 + j) * 4;
        float u0 = fminf(sb[0], ob[0]), u1 = fminf(sb[1], ob[1]);
        float u2 = fmaxf(sb[2], ob[2]), u3 = fmaxf(sb[3], ob[3]);
        float bw = (u2 - u0) / 7.f, bh = (u3 - u1) / 7.f;
        float gx0 = u0 + bw * q, gy0 = u1 + bh * p;
        float inv = 1.f / fmaxf(bw * bh, 1e-8f);
        float oxs = fmaxf(fminf(gx0 + bw, sb[2]) - fmaxf(gx0, sb[0]), 0.f);
        float oys = fmaxf(fminf(gy0 + bh, sb[3]) - fmaxf(gy0, sb[1]), 0.f);
        simap[u * 49 + tid] = oys * oxs * inv;
        float oxo = fmaxf(fminf(gx0 + bw, ob[2]) - fmaxf(gx0, ob[0]), 0.f);
        float oyo = fmaxf(fminf(gy0 + bh, ob[3]) - fmaxf(gy0, ob[1]), 0.f);
        oimap[u * 49 + tid] = oyo * oxo * inv;
    }
}

// ---------------- generic fp32 GEMM: C[m,n] = sum_k A[m,k]*B[k,n] (+bias[m]) ----------------
// grid.z = batch*splitk. splitk>1 => write partials P[kz][M][N] (batch must be 1), no bias.
__global__ __launch_bounds__(256) void gemm_k(
    const float* __restrict__ A, int lda, long sAb,
    const float* __restrict__ B, int ldb, long sBb,
    float* __restrict__ C, int ldc, long sCb,
    const float* __restrict__ bias,
    int M, int N, int K, int splitk) {
    int z = blockIdx.z;
    int bt = z / splitk, kz = z % splitk;
    A += (long)bt * sAb; B += (long)bt * sBb; C += (long)bt * sCb;
    int kchunk = ((K + splitk * 16 - 1) / (splitk * 16)) * 16;
    int k0 = kz * kchunk;
    int k1 = min(K, k0 + kchunk);
    __shared__ float sA[16][68];
    __shared__ float sB[16][68];
    int tid = threadIdx.x;
    int tx = tid & 15, ty = tid >> 4;
    int m0 = blockIdx.y * 64, n0 = blockIdx.x * 64;
    float acc[4][4] = {};
    for (int kt = k0; kt < k1; kt += 16) {
#pragma unroll
        for (int l = 0; l < 4; l++) {
            int e = tid + l * 256;
            int mi = e >> 4, ki = e & 15;
            int m = m0 + mi, k = kt + ki;
            sA[ki][mi] = (m < M && k < k1) ? A[(long)m * lda + k] : 0.f;
        }
#pragma unroll
        for (int l = 0; l < 4; l++) {
            int e = tid + l * 256;
            int ki = e >> 6, ni = e & 63;
            int k = kt + ki, nn = n0 + ni;
            sB[ki][ni] = (k < k1 && nn < N) ? B[(long)k * ldb + nn] : 0.f;
        }
        __syncthreads();
#pragma unroll
        for (int k = 0; k < 16; k++) {
            float a[4], b[4];
#pragma unroll
            for (int i = 0; i < 4; i++) a[i] = sA[k][ty * 4 + i];
#pragma unroll
            for (int j = 0; j < 4; j++) b[j] = sB[k][tx * 4 + j];
#pragma unroll
            for (int i = 0; i < 4; i++)
#pragma unroll
                for (int j = 0; j < 4; j++) acc[i][j] += a[i] * b[j];
        }
        __syncthreads();
    }
    if (splitk > 1) {
        float* Pp_ = C + (long)kz * M * N;
#pragma unroll
        for (int i = 0; i < 4; i++) {
            int m = m0 + ty * 4 + i;
            if (m >= M) continue;
#pragma unroll
            for (int j = 0; j < 4; j++) {
                int nn = n0 + tx * 4 + j;
                if (nn >= N) continue;
                Pp_[(long)m * N + nn] = acc[i][j];
            }
        }
    } else {
#pragma unroll
        for (int i = 0; i < 4; i++) {
            int m = m0 + ty * 4 + i;
            if (m >= M) continue;
            float bv = bias ? bias[m] : 0.f;
#pragma unroll
            for (int j = 0; j < 4; j++) {
                int nn = n0 + tx * 4 + j;
                if (nn >= N) continue;
                C[(long)m * ldc + nn] = acc[i][j] + bv;
            }
        }
    }
}

// ---------------- obj pooling: input -> obj_in rows [0,256) ----------------
__global__ __launch_bounds__(256) void objpool_k(
    const float* __restrict__ input,
    const float* __restrict__ wxo, const float* __restrict__ wyo,
    const float* __restrict__ iao, const int* __restrict__ rngo,
    float* __restrict__ objin) {
    int cg = blockIdx.x;   // 0..31
    int r = blockIdx.y;    // 0..15
    int b = blockIdx.z;    // 0..7
    int rid = b * 16 + r;
    const float* feat = input + (long)b * (Cch * HW) + (long)cg * 8 * HW;
    __shared__ float sF[8192];
    __shared__ float sT[1792];
    __shared__ float sWx[224], sWy[224];
    __shared__ int rng[28];
    int tid = threadIdx.x;
    for (int e = tid; e < 8192; e += 256) sF[e] = feat[e];
    for (int e = tid; e < 224; e += 256) { sWx[e] = wxo[rid * 224 + e]; sWy[e] = wyo[rid * 224 + e]; }
    if (tid < 28) rng[tid] = rngo[rid * 28 + tid];
    __syncthreads();
    for (int e = tid; e < 1792; e += 256) {
        int c = e / 224, rem2 = e % 224, p = rem2 / 32, wc = rem2 % 32;
        int h0 = rng[14 + p], h1 = rng[21 + p];
        float s = 0.f;
        for (int h = h0; h <= h1; h++) s += sF[c * 1024 + h * 32 + wc] * sWy[p * 32 + h];
        sT[e] = s;
    }
    __syncthreads();
    float ia = iao[rid];
    for (int e = tid; e < 392; e += 256) {
        int c = e / 49, rem2 = e % 49, p = rem2 / 7, q = rem2 % 7;
        int w0 = rng[q], w1 = rng[7 + q];
        float s = 0.f;
        for (int wv = w0; wv <= w1; wv++) s += sT[c * 224 + p * 32 + wv] * sWx[q * 32 + wv];
        objin[(long)b * (512 * 784) + (long)(cg * 8 + c) * 784 + r * 49 + rem2] = s * ia;
    }
}

// ---------------- ctx pooling: ctxrel[0:256] with img box -> ctxp ----------------
__global__ __launch_bounds__(256) void ctxpool_k(
    const float* __restrict__ ctxrel,
    const float* __restrict__ wxi, const float* __restrict__ wyi,
    const float* __restrict__ iai, const int* __restrict__ rngi,
    float* __restrict__ ctxp) {
    int cg = blockIdx.x;   // 0..31
    int b = blockIdx.z;    // 0..7
    const float* feat = ctxrel + (long)b * (CCAT * HW) + (long)cg * 8 * HW;
    __shared__ float sF[8192];
    __shared__ float sT[1792];
    __shared__ float sWx[224], sWy[224];
    __shared__ int rng[28];
    int tid = threadIdx.x;
    for (int e = tid; e < 8192; e += 256) sF[e] = feat[e];
    for (int e = tid; e < 224; e += 256) { sWx[e] = wxi[e]; sWy[e] = wyi[e]; }
    if (tid < 28) rng[tid] = rngi[tid];
    __syncthreads();
    for (int e = tid; e < 1792; e += 256) {
        int c = e / 224, rem2 = e % 224, p = rem2 / 32, wc = rem2 % 32;
        int h0 = rng[14 + p], h1 = rng[21 + p];
        float s = 0.f;
        for (int h = h0; h <= h1; h++) s += sF[c * 1024 + h * 32 + wc] * sWy[p * 32 + h];
        sT[e] = s;
    }
    __syncthreads();
    float ia = iai[0];
    for (int e = tid; e < 392; e += 256) {
        int c = e / 49, rem2 = e % 49, p = rem2 / 7, q = rem2 % 7;
        int w0 = rng[q], w1 = rng[7 + q];
        float s = 0.f;
        for (int wv = w0; wv <= w1; wv++) s += sT[c * 224 + p * 32 + wv] * sWx[q * 32 + wv];
        ctxp[(long)b * 12544 + (long)(cg * 8 + c) * 49 + rem2] = s * ia;
    }
}

// ---------------- rel pooling (per image): ctxrel[256:640] over unions -> m_b (imap-scaled) ----------------
__global__ __launch_bounds__(256) void relpool_k(
    const float* __restrict__ ctxrel,
    const float* __restrict__ wxu, const float* __restrict__ wyu,
    const float* __restrict__ iau, const int* __restrict__ rngu,
    const float* __restrict__ simap, const float* __restrict__ oimap,
    float* __restrict__ mb, int b) {
    int cg = blockIdx.x;   // 0..47
    int r = blockIdx.y;    // 0..255
    int rid = b * 256 + r;
    const float* feat = ctxrel + (long)b * (CCAT * HW) + (long)(256 + cg * 8) * HW;
    __shared__ float sF[8192];
    __shared__ float sT[1792];
    __shared__ float sWx[224], sWy[224];
    __shared__ float sSI[49], sOI[49];
    __shared__ int rng[28];
    int tid = threadIdx.x;
    for (int e = tid; e < 8192; e += 256) sF[e] = feat[e];
    for (int e = tid; e < 224; e += 256) { sWx[e] = wxu[rid * 224 + e]; sWy[e] = wyu[rid * 224 + e]; }
    if (tid < 49) { sSI[tid] = simap[rid * 49 + tid]; sOI[tid] = oimap[rid * 49 + tid]; }
    if (tid < 28) rng[tid] = rngu[rid * 28 + tid];
    __syncthreads();
    for (int e = tid; e < 1792; e += 256) {
        int c = e / 224, rem2 = e % 224, p = rem2 / 32, wc = rem2 % 32;
        int h0 = rng[14 + p], h1 = rng[21 + p];
        float s = 0.f;
        for (int h = h0; h <= h1; h++) s += sF[c * 1024 + h * 32 + wc] * sWy[p * 32 + h];
        sT[e] = s;
    }
    __syncthreads();
    float ia = iau[rid];
    for (int e = tid; e < 392; e += 256) {
        int c = e / 49, rem2 = e % 49, p = rem2 / 7, q = rem2 % 7;
        int w0 = rng[q], w1 = rng[7 + q];
        float s = 0.f;
        for (int wv = w0; wv <= w1; wv++) s += sT[c * 224 + p * 32 + wv] * sWx[q * 32 + wv];
        s *= ia;
        int cglob = cg * 8 + c;
        if (cglob >= 128 && cglob < 256) s *= sSI[rem2];
        else if (cglob >= 256) s *= sOI[rem2];
        mb[(long)cglob * KFC + r * 49 + rem2] = s;
    }
}

// ---------------- obj_in rows [256,512): x_c broadcast + y_c * box_imap ----------------
__global__ void objin_fill_k(const float* __restrict__ ctxp, const float* __restrict__ bimap,
                             float* __restrict__ objin) {
    int t = blockIdx.x * 256 + threadIdx.x;
    if (t >= 8 * 256 * 784) return;
    int b = t / (256 * 784);
    int rem = t % (256 * 784);
    int j = rem / 784, col = rem % 784;
    int r = col / 49, pq = col % 49;
    float v = ctxp[(long)b * 12544 + j * 49 + pq];
    if (j >= 128) v *= bimap[(b * 16 + r) * 49 + pq];
    objin[(long)b * (512 * 784) + (long)(256 + j) * 784 + col] = v;
}

// ---------------- X_o[k][b*16+i] = relu(obj_feat) ----------------
__global__ void xo_fill_k(const float* __restrict__ objf, float* __restrict__ xo) {
    int k = blockIdx.x;        // 0..12543
    int col = threadIdx.x;     // 0..127
    int b = col >> 4, i = col & 15;
    int d = k / 49, pq = k % 49;
    xo[(long)k * 128 + col] = fmaxf(objf[(long)b * 200704 + d * 784 + i * 49 + pq], 0.f);
}

// ---------------- X_b[k][pair] = relu(C1 + As[sub] + Ao[obj]) ----------------
__global__ void combine_k(const float* __restrict__ c1b, const float* __restrict__ as_,
                          const float* __restrict__ ao_, float* __restrict__ xb, int b) {
    int k = blockIdx.x;        // 0..12543
    int pair = threadIdx.x;    // 0..255
    int d = k / 49, pq = k % 49;
    int i = pair >> 4, j = pair & 15;
    float v = c1b[(long)d * KFC + pair * 49 + pq]
            + as_[(long)b * 200704 + d * 784 + i * 49 + pq]
            + ao_[(long)b * 200704 + d * 784 + j * 49 + pq];
    xb[(long)k * 256 + pair] = fmaxf(v, 0.f);
}

// ---------------- reduce split-K partials + bias, write transposed [n][m] ----------------
__global__ void reduce_bias_t_k(const float* __restrict__ Pd, const float* __restrict__ bias,
                                float* __restrict__ outT, int M, int N, int splitk) {
    int t = blockIdx.x * 256 + threadIdx.x;
    if (t >= M * N) return;
    int nn = t / M, m = t % M;
    float s = bias[m];
    for (int z = 0; z < splitk; z++) s += Pd[(long)z * M * N + (long)m * N + nn];
    outT[t] = s;
}

// ---------------- L2 normalize 256-vectors and store ----------------
__global__ void norm_store_k(const float* __restrict__ inT, float* __restrict__ out, long outBase) {
    int vec = blockIdx.x, tid = threadIdx.x;
    float v = inT[(long)vec * 256 + tid];
    float s = v * v;
    for (int o = 32; o > 0; o >>= 1) s += __shfl_down(s, o, 64);
    __shared__ float red[4];
    if ((tid & 63) == 0) red[tid >> 6] = s;
    __syncthreads();
    float tot = red[0] + red[1] + red[2] + red[3];
    out[outBase + (long)vec * 256 + tid] = v / sqrtf(tot);
}

extern "C" void kernel_launch(void* const* d_in, const int* in_sizes, int n_in,
                              void* d_out, int out_size, void* d_ws, size_t ws_size,
                              hipStream_t stream) {
    const float* input = (const float*)d_in[0];
    const float* objects = (const float*)d_in[1];
    const float* Wc = (const float*)d_in[3];
    const float* bc = (const float*)d_in[4];
    const float* Wr = (const float*)d_in[5];
    const float* br = (const float*)d_in[6];
    const float* Wof = (const float*)d_in[7];
    const float* bof = (const float*)d_in[8];
    const float* Wrf = (const float*)d_in[9];
    const float* brf = (const float*)d_in[10];
    const float* Wofc = (const float*)d_in[11];
    const float* bofc = (const float*)d_in[12];
    const float* Wrfc = (const float*)d_in[13];
    const float* brfc = (const float*)d_in[14];
    float* out = (float*)d_out;

    float* w = (float*)d_ws;
    size_t off = 0;
    auto alloc = [&](size_t nf) { float* p = w + off; off += nf; return p; };
    float* WCAT = alloc(CCAT * Cch);
    float* BCAT = alloc(CCAT);
    float* CTXREL = alloc((size_t)Bimg * CCAT * HW);
    float* WXO = alloc(128 * 224); float* WYO = alloc(128 * 224); float* IAO = alloc(128);
    int* RNGO = (int*)alloc(128 * 28);
    float* WXU = alloc(2048 * 224); float* WYU = alloc(2048 * 224); float* IAU = alloc(2048);
    int* RNGU = (int*)alloc(2048 * 28);
    float* WXI = alloc(224); float* WYI = alloc(224); float* IAI = alloc(1);
    int* RNGI = (int*)alloc(28);
    float* BIMAP = alloc(128 * 49);
    float* SIMAP = alloc(2048 * 49);
    float* OIMAP = alloc(2048 * 49);
    float* CTXP = alloc(Bimg * 256 * 49);
    float* OBJIN = alloc((size_t)Bimg * 512 * 784);
    float* OBJF = alloc((size_t)Bimg * 256 * 784);
    float* AS = alloc((size_t)Bimg * 256 * 784);
    float* AO = alloc((size_t)Bimg * 256 * 784);
    float* MB = alloc((size_t)CREL * KFC);    // per-image rel_pool out; also aliased below
    float* C1B = alloc((size_t)256 * KFC);    // per-image; also aliased below
    // aliases (lifetimes disjoint):
    float* XO = MB;                              // [12544][128]
    float* OPART = MB + (size_t)KFC * 128;       // [32][256][128]
    float* OT = OPART + (size_t)32 * 256 * 128;  // [128][256]
    float* XB = MB;                              // [12544][256]
    float* RPART = C1B;                          // [16][256][256]
    float* RT = C1B + (size_t)16 * 256 * 256;    // [256][256]

    // 1. weight concat
    catw_k<<<dim3((CCAT * Cch + 255) / 256), 256, 0, stream>>>(Wc, bc, Wr, br, WCAT, BCAT);
    // 2. axis weights for all rois (128 obj + 2048 unions + img)
    axisw_k<<<dim3(2177), 64, 0, stream>>>(objects, WXO, WYO, IAO, RNGO,
                                           WXU, WYU, IAU, RNGU, WXI, WYI, IAI, RNGI);
    // 3. intersection maps
    imap_k<<<dim3(128 + 2048), 64, 0, stream>>>(objects, BIMAP, SIMAP, OIMAP);
    // 4. ctx_all + rel_all = Wcat @ input  [8][640][1024]
    gemm_k<<<dim3(16, 10, 8), 256, 0, stream>>>(WCAT, Cch, 0L, input, HW, (long)Cch * HW,
                                                CTXREL, HW, (long)CCAT * HW, BCAT,
                                                CCAT, HW, Cch, 1);
    // 5. obj_pool -> obj_in rows [0,256)
    objpool_k<<<dim3(32, 16, 8), 256, 0, stream>>>(input, WXO, WYO, IAO, RNGO, OBJIN);
    // 6. ctx_pool
    ctxpool_k<<<dim3(32, 1, 8), 256, 0, stream>>>(CTXREL, WXI, WYI, IAI, RNGI, CTXP);
    // 7. obj_in rows [256,512)
    objin_fill_k<<<dim3((8 * 256 * 784 + 255) / 256), 256, 0, stream>>>(CTXP, BIMAP, OBJIN);
    // 8. obj_feat = Wof @ obj_in + bof
    gemm_k<<<dim3(13, 4, 8), 256, 0, stream>>>(Wof, 512, 0L, OBJIN, 784, 512L * 784,
                                               OBJF, 784, 256L * 784, bof, 256, 784, 512, 1);
    // 9/10. As = Wrf[:,0:256] @ obj_feat ; Ao = Wrf[:,256:512] @ obj_feat
    gemm_k<<<dim3(13, 4, 8), 256, 0, stream>>>(Wrf, 896, 0L, OBJF, 784, 256L * 784,
                                               AS, 784, 256L * 784, nullptr, 256, 784, 256, 1);
    gemm_k<<<dim3(13, 4, 8), 256, 0, stream>>>(Wrf + 256, 896, 0L, OBJF, 784, 256L * 784,
                                               AO, 784, 256L * 784, nullptr, 256, 784, 256, 1);
    // 11. X_o = relu(obj_feat) transposed to [k][128]
    xo_fill_k<<<dim3(KFC), 128, 0, stream>>>(OBJF, XO);
    // 12. o partials = Wofc @ X_o (split-K 32)
    gemm_k<<<dim3(2, 4, 32), 256, 0, stream>>>(Wofc, KFC, 0L, XO, 128, 0L,
                                               OPART, 128, 0L, nullptr, 256, 128, KFC, 32);
    // 13. reduce + bofc -> OT[col][dout]
    reduce_bias_t_k<<<dim3((256 * 128 + 255) / 256), 256, 0, stream>>>(OPART, bofc, OT, 256, 128, 32);
    // 14. normalize + store obj_out
    norm_store_k<<<dim3(128), 256, 0, stream>>>(OT, out, 0L);

    // per-image rel path
    for (int b = 0; b < Bimg; b++) {
        relpool_k<<<dim3(48, 256), 256, 0, stream>>>(CTXREL, WXU, WYU, IAU, RNGU,
                                                     SIMAP, OIMAP, MB, b);
        gemm_k<<<dim3(196, 4, 1), 256, 0, stream>>>(Wrf + 512, 896, 0L, MB, KFC, 0L,
                                                    C1B, KFC, 0L, brf, 256, KFC, CREL, 1);
        combine_k<<<dim3(KFC), 256, 0, stream>>>(C1B, AS, AO, XB, b);
        gemm_k<<<dim3(4, 4, 16), 256, 0, stream>>>(Wrfc, KFC, 0L, XB, 256, 0L,
                                                   RPART, 256, 0L, nullptr, 256, 256, KFC, 16);
        reduce_bias_t_k<<<dim3((256 * 256 + 255) / 256), 256, 0, stream>>>(RPART, brfc, RT, 256, 256, 16);
        norm_store_k<<<dim3(256), 256, 0, stream>>>(RT, out, 32768L + (long)b * 65536L);
    }
}

// Round 2
// 1572.819 us; speedup vs baseline: 1.8930x; 1.8930x over previous
//
#include <hip/hip_runtime.h>
#include <hip/hip_bf16.h>

// SceneGraph head: conv1x1 -> PrRoIPool (exact separable) -> channel matmuls -> FC -> L2norm
// Round 2: bf16 MFMA (16x16x32) for obj_feat, C1B(fused epilogue), o-fc, r-fc.
// Producers write B^T bf16 (K-contiguous) so both MFMA operands stage identically.

#define Bimg 8
#define Cch 256
#define HW 1024
#define Pp 7
#define PQ 49
#define CREL 384
#define CCAT 640
#define KFC 12544

typedef __hip_bfloat16 bf16;
typedef __attribute__((ext_vector_type(8))) short short8;
typedef __attribute__((ext_vector_type(4))) float f32x4;

__device__ __forceinline__ float hat_int(float t) {
    t = fminf(1.f, fmaxf(-1.f, t));
    return (t < 0.f) ? 0.5f * (t + 1.f) * (t + 1.f) : 1.f - 0.5f * (1.f - t) * (1.f - t);
}

// ---------------- weight concat (Wc over Wr) ----------------
__global__ void catw_k(const float* __restrict__ Wc, const float* __restrict__ bc,
                       const float* __restrict__ Wr, const float* __restrict__ br,
                       float* __restrict__ Wcat, float* __restrict__ bcat) {
    int t = blockIdx.x * 256 + threadIdx.x;
    if (t < CCAT * Cch) {
        int d = t / Cch, c = t % Cch;
        Wcat[t] = (d < Cch) ? Wc[d * Cch + c] : Wr[(d - Cch) * Cch + c];
    }
    if (t < CCAT) bcat[t] = (t < Cch) ? bc[t] : br[t - Cch];
}

// ---------------- fp32 -> bf16 convert ----------------
__global__ void f2b_k(const float* __restrict__ s, bf16* __restrict__ d, int n) {
    int t = blockIdx.x * 256 + threadIdx.x;
    if (t < n) d[t] = __float2bfloat16(s[t]);
}
// Wrf cols [512:896) -> [256][384] bf16
__global__ void wrfxyz_k(const float* __restrict__ Wrf, bf16* __restrict__ dst) {
    int t = blockIdx.x * 256 + threadIdx.x;
    if (t >= 256 * 384) return;
    int d = t / 384, k = t % 384;
    dst[t] = __float2bfloat16(Wrf[d * 896 + 512 + k]);
}

// ---------------- per-roi axis weights + support ranges + inv-area ----------------
__global__ void axisw_k(const float* __restrict__ objects,
                        float* wxo, float* wyo, float* iao, int* rngo,
                        float* wxu, float* wyu, float* iau, int* rngu,
                        float* wxi, float* wyi, float* iai, int* rngi) {
    int bid = blockIdx.x;
    float b0, b1, b2, b3;
    float *wx, *wy, *ia;
    int* rng;
    if (bid < 128) {
        b0 = objects[bid * 4]; b1 = objects[bid * 4 + 1];
        b2 = objects[bid * 4 + 2]; b3 = objects[bid * 4 + 3];
        wx = wxo + bid * 224; wy = wyo + bid * 224; ia = iao + bid; rng = rngo + bid * 28;
    } else if (bid < 128 + 2048) {
        int u = bid - 128;
        int img = u >> 8, pair = u & 255, i = pair >> 4, j = pair & 15;
        const float* sb = objects + (img * 16 + i) * 4;
        const float* ob = objects + (img * 16 + j) * 4;
        b0 = fminf(sb[0], ob[0]); b1 = fminf(sb[1], ob[1]);
        b2 = fmaxf(sb[2], ob[2]); b3 = fmaxf(sb[3], ob[3]);
        wx = wxu + u * 224; wy = wyu + u * 224; ia = iau + u; rng = rngu + u * 28;
    } else {
        b0 = 0.f; b1 = 0.f; b2 = 512.f; b3 = 512.f;
        wx = wxi; wy = wyi; ia = iai; rng = rngi;
    }
    const float sc = 0.0625f;
    int tid = threadIdx.x;
    {   // x axis
        float lo = b0 * sc, hi = b2 * sc, bw = (hi - lo) * (1.f / 7.f);
        for (int e = tid; e < 224; e += 64) {
            int p = e / 32, i2 = e % 32;
            float st = lo + bw * p, en = st + bw;
            wx[e] = hat_int(en - (float)i2) - hat_int(st - (float)i2);
        }
        if (tid < 7) {
            float st = lo + bw * tid, en = st + bw;
            rng[tid] = max(0, (int)floorf(st) - 1);
            rng[7 + tid] = min(31, (int)ceilf(en) + 1);
        }
    }
    {   // y axis
        float lo = b1 * sc, hi = b3 * sc, bw = (hi - lo) * (1.f / 7.f);
        for (int e = tid; e < 224; e += 64) {
            int p = e / 32, i2 = e % 32;
            float st = lo + bw * p, en = st + bw;
            wy[e] = hat_int(en - (float)i2) - hat_int(st - (float)i2);
        }
        if (tid < 7) {
            float st = lo + bw * tid, en = st + bw;
            rng[14 + tid] = max(0, (int)floorf(st) - 1);
            rng[21 + tid] = min(31, (int)ceilf(en) + 1);
        }
    }
    if (tid == 0) {
        float bwx = (b2 - b0) * sc * (1.f / 7.f), bwy = (b3 - b1) * sc * (1.f / 7.f);
        *ia = 1.f / fmaxf(bwx * bwy, 1e-8f);
    }
}

// ---------------- intersection maps ----------------
__global__ void imap_k(const float* __restrict__ objects,
                       float* __restrict__ bimap, float* __restrict__ simap,
                       float* __restrict__ oimap) {
    int bid = blockIdx.x;
    int tid = threadIdx.x;
    if (tid >= 49) return;
    int p = tid / 7, q = tid % 7;
    if (bid < 128) {
        float a0 = objects[bid * 4], a1 = objects[bid * 4 + 1];
        float a2 = objects[bid * 4 + 2], a3 = objects[bid * 4 + 3];
        float bw = 512.f / 7.f, bh = 512.f / 7.f;
        float gx0 = bw * q, gy0 = bh * p;
        float ox = fmaxf(fminf(gx0 + bw, a2) - fmaxf(gx0, a0), 0.f);
        float oy = fmaxf(fminf(gy0 + bh, a3) - fmaxf(gy0, a1), 0.f);
        bimap[bid * 49 + tid] = oy * ox / fmaxf(bw * bh, 1e-8f);
    } else {
        int u = bid - 128;
        int img = u >> 8, pair = u & 255, i = pair >> 4, j = pair & 15;
        const float* sb = objects + (img * 16 + i) * 4;
        const float* ob = objects + (img * 16 + j) * 4;
        float u0 = fminf(sb[0], ob[0]), u1 = fminf(sb[1], ob[1]);
        float u2 = fmaxf(sb[2], ob[2]), u3 = fmaxf(sb[3], ob[3]);
        float bw = (u2 - u0) / 7.f, bh = (u3 - u1) / 7.f;
        float gx0 = u0 + bw * q, gy0 = u1 + bh * p;
        float inv = 1.f / fmaxf(bw * bh, 1e-8f);
        float oxs = fmaxf(fminf(gx0 + bw, sb[2]) - fmaxf(gx0, sb[0]), 0.f);
        float oys = fmaxf(fminf(gy0 + bh, sb[3]) - fmaxf(gy0, sb[1]), 0.f);
        simap[u * 49 + tid] = oys * oxs * inv;
        float oxo = fmaxf(fminf(gx0 + bw, ob[2]) - fmaxf(gx0, ob[0]), 0.f);
        float oyo = fmaxf(fminf(gy0 + bh, ob[3]) - fmaxf(gy0, ob[1]), 0.f);
        oimap[u * 49 + tid] = oyo * oxo * inv;
    }
}

// ---------------- generic fp32 GEMM (kept for conv / As / Ao) ----------------
__global__ __launch_bounds__(256) void gemm_k(
    const float* __restrict__ A, int lda, long sAb,
    const float* __restrict__ B, int ldb, long sBb,
    float* __restrict__ C, int ldc, long sCb,
    const float* __restrict__ bias,
    int M, int N, int K) {
    int bt = blockIdx.z;
    A += (long)bt * sAb; B += (long)bt * sBb; C += (long)bt * sCb;
    __shared__ float sA[16][68];
    __shared__ float sB[16][68];
    int tid = threadIdx.x;
    int tx = tid & 15, ty = tid >> 4;
    int m0 = blockIdx.y * 64, n0 = blockIdx.x * 64;
    float acc[4][4] = {};
    for (int kt = 0; kt < K; kt += 16) {
#pragma unroll
        for (int l = 0; l < 4; l++) {
            int e = tid + l * 256;
            int mi = e >> 4, ki = e & 15;
            int m = m0 + mi, k = kt + ki;
            sA[ki][mi] = (m < M && k < K) ? A[(long)m * lda + k] : 0.f;
        }
#pragma unroll
        for (int l = 0; l < 4; l++) {
            int e = tid + l * 256;
            int ki = e >> 6, ni = e & 63;
            int k = kt + ki, nn = n0 + ni;
            sB[ki][ni] = (k < K && nn < N) ? B[(long)k * ldb + nn] : 0.f;
        }
        __syncthreads();
#pragma unroll
        for (int k = 0; k < 16; k++) {
            float a[4], b[4];
#pragma unroll
            for (int i = 0; i < 4; i++) a[i] = sA[k][ty * 4 + i];
#pragma unroll
            for (int j = 0; j < 4; j++) b[j] = sB[k][tx * 4 + j];
#pragma unroll
            for (int i = 0; i < 4; i++)
#pragma unroll
                for (int j = 0; j < 4; j++) acc[i][j] += a[i] * b[j];
        }
        __syncthreads();
    }
#pragma unroll
    for (int i = 0; i < 4; i++) {
        int m = m0 + ty * 4 + i;
        if (m >= M) continue;
        float bv = bias ? bias[m] : 0.f;
#pragma unroll
        for (int j = 0; j < 4; j++) {
            int nn = n0 + tx * 4 + j;
            if (nn >= N) continue;
            C[(long)m * ldc + nn] = acc[i][j] + bv;
        }
    }
}

// ---------------- bf16 MFMA GEMM: C[m,n] = sum_k A[m,k] * BT[n,k] ----------------
// 128x128 tile, BK=32, 256 threads (2x2 waves of 64x64). M,N multiples of 128, K of 32.
// mode 0: Cf[m*ldc+n] = acc + bias[m]
// mode 1: fused rel epilogue -> XBt bf16 (relu(acc + bias + AS + AO)), transposed
// mode 2: split-K partials Cf[kz][Mtot][Ntot]
__global__ __launch_bounds__(256) void mfma_gemm_k(
    const bf16* __restrict__ A, int lda,
    const bf16* __restrict__ BT, int ldbt,
    int Ktiles, int splitk, int mode,
    float* __restrict__ Cf, int ldc, int Mtot, int Ntot,
    const float* __restrict__ bias,
    const float* __restrict__ AS2, const float* __restrict__ AO2, int bimg,
    bf16* __restrict__ XBt) {
    __shared__ short sA[128 * 40];   // +8 pad per row: 2-way-max LDS conflicts
    __shared__ short sB[128 * 40];
    const int tid = threadIdx.x;
    const int m0 = blockIdx.y * 128, n0 = blockIdx.x * 128;
    const int kz = blockIdx.z;
    const int tp = (Ktiles + splitk - 1) / splitk;
    const int kt0 = kz * tp;
    const int kt1 = min(Ktiles, kt0 + tp);
    const int srow = tid >> 2, scol = (tid & 3) * 8;
    const int lane = tid & 63, wid = tid >> 6;
    const int wm = (wid >> 1) * 64, wn = (wid & 1) * 64;
    const int lrow = lane & 15, lk = (lane >> 4) * 8;
    f32x4 acc[4][4];
#pragma unroll
    for (int i = 0; i < 4; i++)
#pragma unroll
        for (int j = 0; j < 4; j++) acc[i][j] = (f32x4){0.f, 0.f, 0.f, 0.f};
    const bf16* gA = A + (size_t)(m0 + srow) * lda + scol;
    const bf16* gB = BT + (size_t)(n0 + srow) * ldbt + scol;
    for (int kt = kt0; kt < kt1; kt++) {
        short8 a0 = *(const short8*)(gA + (size_t)kt * 32);
        short8 a1 = *(const short8*)(gA + (size_t)64 * lda + (size_t)kt * 32);
        short8 b0 = *(const short8*)(gB + (size_t)kt * 32);
        short8 b1 = *(const short8*)(gB + (size_t)64 * ldbt + (size_t)kt * 32);
        __syncthreads();
        *(short8*)&sA[srow * 40 + scol] = a0;
        *(short8*)&sA[(srow + 64) * 40 + scol] = a1;
        *(short8*)&sB[srow * 40 + scol] = b0;
        *(short8*)&sB[(srow + 64) * 40 + scol] = b1;
        __syncthreads();
        short8 af[4], bfr[4];
#pragma unroll
        for (int f = 0; f < 4; f++) {
            af[f] = *(const short8*)&sA[(wm + f * 16 + lrow) * 40 + lk];
            bfr[f] = *(const short8*)&sB[(wn + f * 16 + lrow) * 40 + lk];
        }
#pragma unroll
        for (int i = 0; i < 4; i++)
#pragma unroll
            for (int j = 0; j < 4; j++)
                acc[i][j] = __builtin_amdgcn_mfma_f32_16x16x32_bf16(af[i], bfr[j], acc[i][j], 0, 0, 0);
    }
    const int rbase = (lane >> 4) * 4, cf = lane & 15;
    if (mode == 2) {
        float* P = Cf + (size_t)kz * Mtot * Ntot;
#pragma unroll
        for (int i = 0; i < 4; i++)
#pragma unroll
            for (int reg = 0; reg < 4; reg++) {
                int m = m0 + wm + i * 16 + rbase + reg;
#pragma unroll
                for (int j = 0; j < 4; j++) {
                    int n = n0 + wn + j * 16 + cf;
                    P[(size_t)m * Ntot + n] = acc[i][j][reg];
                }
            }
    } else if (mode == 0) {
#pragma unroll
        for (int i = 0; i < 4; i++)
#pragma unroll
            for (int reg = 0; reg < 4; reg++) {
                int m = m0 + wm + i * 16 + rbase + reg;
                float bv = bias ? bias[m] : 0.f;
#pragma unroll
                for (int j = 0; j < 4; j++) {
                    int n = n0 + wn + j * 16 + cf;
                    Cf[(size_t)m * ldc + n] = acc[i][j][reg] + bv;
                }
            }
    } else {  // mode 1: rel C1 fused epilogue
#pragma unroll
        for (int i = 0; i < 4; i++)
#pragma unroll
            for (int reg = 0; reg < 4; reg++) {
                int m = m0 + wm + i * 16 + rbase + reg;  // d (out channel)
                float bv = bias[m];
#pragma unroll
                for (int j = 0; j < 4; j++) {
                    int n = n0 + wn + j * 16 + cf;       // col = r*49 + pq
                    int r = n / 49;
                    int pq = n - r * 49;
                    int ii = r >> 4, jj = r & 15;
                    float v = acc[i][j][reg] + bv
                            + AS2[(size_t)m * 6272 + bimg * 784 + ii * 49 + pq]
                            + AO2[(size_t)m * 6272 + bimg * 784 + jj * 49 + pq];
                    XBt[(size_t)r * KFC + m * 49 + pq] = __float2bfloat16(fmaxf(v, 0.f));
                }
            }
    }
}

// ---------------- obj pooling: input -> OBJINt[col][ch 0..255] bf16 ----------------
__global__ __launch_bounds__(256) void objpool_k(
    const float* __restrict__ input,
    const float* __restrict__ wxo, const float* __restrict__ wyo,
    const float* __restrict__ iao, const int* __restrict__ rngo,
    bf16* __restrict__ objint) {
    int cg = blockIdx.x;   // 0..31
    int r = blockIdx.y;    // 0..15
    int b = blockIdx.z;    // 0..7
    int rid = b * 16 + r;
    const float* feat = input + (long)b * (Cch * HW) + (long)cg * 8 * HW;
    __shared__ float sF[8192];
    __shared__ float sT[1792];
    __shared__ float sWx[224], sWy[224];
    __shared__ int rng[28];
    int tid = threadIdx.x;
    for (int e = tid; e < 8192; e += 256) sF[e] = feat[e];
    for (int e = tid; e < 224; e += 256) { sWx[e] = wxo[rid * 224 + e]; sWy[e] = wyo[rid * 224 + e]; }
    if (tid < 28) rng[tid] = rngo[rid * 28 + tid];
    __syncthreads();
    for (int e = tid; e < 1792; e += 256) {
        int c = e / 224, rem2 = e % 224, p = rem2 / 32, wc = rem2 % 32;
        int h0 = rng[14 + p], h1 = rng[21 + p];
        float s = 0.f;
        for (int h = h0; h <= h1; h++) s += sF[c * 1024 + h * 32 + wc] * sWy[p * 32 + h];
        sT[e] = s;
    }
    __syncthreads();
    float ia = iao[rid];
    for (int e = tid; e < 392; e += 256) {
        int c = e / 49, rem2 = e % 49, p = rem2 / 7, q = rem2 % 7;
        int w0 = rng[q], w1 = rng[7 + q];
        float s = 0.f;
        for (int wv = w0; wv <= w1; wv++) s += sT[c * 224 + p * 32 + wv] * sWx[q * 32 + wv];
        objint[((long)b * 784 + r * 49 + rem2) * 512 + cg * 8 + c] = __float2bfloat16(s * ia);
    }
}

// ---------------- ctx pooling: ctxrel[0:256] with img box -> ctxp (fp32) ----------------
__global__ __launch_bounds__(256) void ctxpool_k(
    const float* __restrict__ ctxrel,
    const float* __restrict__ wxi, const float* __restrict__ wyi,
    const float* __restrict__ iai, const int* __restrict__ rngi,
    float* __restrict__ ctxp) {
    int cg = blockIdx.x;   // 0..31
    int b = blockIdx.z;    // 0..7
    const float* feat = ctxrel + (long)b * (CCAT * HW) + (long)cg * 8 * HW;
    __shared__ float sF[8192];
    __shared__ float sT[1792];
    __shared__ float sWx[224], sWy[224];
    __shared__ int rng[28];
    int tid = threadIdx.x;
    for (int e = tid; e < 8192; e += 256) sF[e] = feat[e];
    for (int e = tid; e < 224; e += 256) { sWx[e] = wxi[e]; sWy[e] = wyi[e]; }
    if (tid < 28) rng[tid] = rngi[tid];
    __syncthreads();
    for (int e = tid; e < 1792; e += 256) {
        int c = e / 224, rem2 = e % 224, p = rem2 / 32, wc = rem2 % 32;
        int h0 = rng[14 + p], h1 = rng[21 + p];
        float s = 0.f;
        for (int h = h0; h <= h1; h++) s += sF[c * 1024 + h * 32 + wc] * sWy[p * 32 + h];
        sT[e] = s;
    }
    __syncthreads();
    float ia = iai[0];
    for (int e = tid; e < 392; e += 256) {
        int c = e / 49, rem2 = e % 49, p = rem2 / 7, q = rem2 % 7;
        int w0 = rng[q], w1 = rng[7 + q];
        float s = 0.f;
        for (int wv = w0; wv <= w1; wv++) s += sT[c * 224 + p * 32 + wv] * sWx[q * 32 + wv];
        ctxp[(long)b * 12544 + (long)(cg * 8 + c) * 49 + rem2] = s * ia;
    }
}

// ---------------- rel pooling (per image): -> MBt[col][ch 0..383] bf16 (imap-scaled) ----------------
__global__ __launch_bounds__(256) void relpool_k(
    const float* __restrict__ ctxrel,
    const float* __restrict__ wxu, const float* __restrict__ wyu,
    const float* __restrict__ iau, const int* __restrict__ rngu,
    const float* __restrict__ simap, const float* __restrict__ oimap,
    bf16* __restrict__ mbt, int b) {
    int cg = blockIdx.x;   // 0..47
    int r = blockIdx.y;    // 0..255
    int rid = b * 256 + r;
    const float* feat = ctxrel + (long)b * (CCAT * HW) + (long)(256 + cg * 8) * HW;
    __shared__ float sF[8192];
    __shared__ float sT[1792];
    __shared__ float sWx[224], sWy[224];
    __shared__ float sSI[49], sOI[49];
    __shared__ int rng[28];
    int tid = threadIdx.x;
    for (int e = tid; e < 8192; e += 256) sF[e] = feat[e];
    for (int e = tid; e < 224; e += 256) { sWx[e] = wxu[rid * 224 + e]; sWy[e] = wyu[rid * 224 + e]; }
    if (tid < 49) { sSI[tid] = simap[rid * 49 + tid]; sOI[tid] = oimap[rid * 49 + tid]; }
    if (tid < 28) rng[tid] = rngu[rid * 28 + tid];
    __syncthreads();
    for (int e = tid; e < 1792; e += 256) {
        int c = e / 224, rem2 = e % 224, p = rem2 / 32, wc = rem2 % 32;
        int h0 = rng[14 + p], h1 = rng[21 + p];
        float s = 0.f;
        for (int h = h0; h <= h1; h++) s += sF[c * 1024 + h * 32 + wc] * sWy[p * 32 + h];
        sT[e] = s;
    }
    __syncthreads();
    float ia = iau[rid];
    for (int e = tid; e < 392; e += 256) {
        int c = e / 49, rem2 = e % 49, p = rem2 / 7, q = rem2 % 7;
        int w0 = rng[q], w1 = rng[7 + q];
        float s = 0.f;
        for (int wv = w0; wv <= w1; wv++) s += sT[c * 224 + p * 32 + wv] * sWx[q * 32 + wv];
        s *= ia;
        int cglob = cg * 8 + c;
        if (cglob >= 128 && cglob < 256) s *= sSI[rem2];
        else if (cglob >= 256) s *= sOI[rem2];
        mbt[((long)r * 49 + rem2) * 384 + cglob] = __float2bfloat16(s);
    }
}

// ---------------- OBJINt ch [256,512): x_c broadcast + y_c * box_imap ----------------
__global__ void objin_fill_k(const float* __restrict__ ctxp, const float* __restrict__ bimap,
                             bf16* __restrict__ objint) {
    int t = blockIdx.x * 256 + threadIdx.x;
    if (t >= 8 * 256 * 784) return;
    int b = t / (256 * 784);
    int rem = t % (256 * 784);
    int j = rem / 784, col = rem % 784;
    int r = col / 49, pq = col % 49;
    float v = ctxp[(long)b * 12544 + j * 49 + pq];
    if (j >= 128) v *= bimap[(b * 16 + r) * 49 + pq];
    objint[((long)b * 784 + col) * 512 + 256 + j] = __float2bfloat16(v);
}

// ---------------- XOt[col][k] = relu(OBJF2) bf16 ----------------
__global__ void xo_pack_k(const float* __restrict__ objf2, bf16* __restrict__ xot) {
    int col = blockIdx.y;                       // 0..127 (b*16+i)
    int k = blockIdx.x * 256 + threadIdx.x;     // 0..12543 (d*49+pq)
    int d = k / 49, pq = k - d * 49;
    int b = col >> 4, i = col & 15;
    xot[(long)col * KFC + k] =
        __float2bfloat16(fmaxf(objf2[(long)d * 6272 + b * 784 + i * 49 + pq], 0.f));
}

// ---------------- reduce split-K partials + bias, write transposed [n][m] ----------------
__global__ void reduce_bias_t_k(const float* __restrict__ Pd, const float* __restrict__ bias,
                                float* __restrict__ outT, int M, int N, int splitk) {
    int t = blockIdx.x * 256 + threadIdx.x;
    if (t >= M * N) return;
    int nn = t / M, m = t % M;
    float s = bias[m];
    for (int z = 0; z < splitk; z++) s += Pd[(long)z * M * N + (long)m * N + nn];
    outT[t] = s;
}

// ---------------- L2 normalize 256-vectors and store ----------------
__global__ void norm_store_k(const float* __restrict__ inT, float* __restrict__ out, long outBase) {
    int vec = blockIdx.x, tid = threadIdx.x;
    float v = inT[(long)vec * 256 + tid];
    float s = v * v;
    for (int o = 32; o > 0; o >>= 1) s += __shfl_down(s, o, 64);
    __shared__ float red[4];
    if ((tid & 63) == 0) red[tid >> 6] = s;
    __syncthreads();
    float tot = red[0] + red[1] + red[2] + red[3];
    out[outBase + (long)vec * 256 + tid] = v / sqrtf(tot);
}

extern "C" void kernel_launch(void* const* d_in, const int* in_sizes, int n_in,
                              void* d_out, int out_size, void* d_ws, size_t ws_size,
                              hipStream_t stream) {
    const float* input = (const float*)d_in[0];
    const float* objects = (const float*)d_in[1];
    const float* Wc = (const float*)d_in[3];
    const float* bc = (const float*)d_in[4];
    const float* Wr = (const float*)d_in[5];
    const float* br = (const float*)d_in[6];
    const float* Wof = (const float*)d_in[7];
    const float* bof = (const float*)d_in[8];
    const float* Wrf = (const float*)d_in[9];
    const float* brf = (const float*)d_in[10];
    const float* Wofc = (const float*)d_in[11];
    const float* bofc = (const float*)d_in[12];
    const float* Wrfc = (const float*)d_in[13];
    const float* brfc = (const float*)d_in[14];
    float* out = (float*)d_out;

    float* w = (float*)d_ws;
    size_t off = 0;
    auto alloc = [&](size_t nf) { nf = (nf + 3) & ~(size_t)3; float* p = w + off; off += nf; return p; };
    float* WCAT = alloc(CCAT * Cch);
    float* BCAT = alloc(CCAT);
    float* CTXREL = alloc((size_t)Bimg * CCAT * HW);
    float* WXO = alloc(128 * 224); float* WYO = alloc(128 * 224); float* IAO = alloc(128);
    int* RNGO = (int*)alloc(128 * 28);
    float* WXU = alloc(2048 * 224); float* WYU = alloc(2048 * 224); float* IAU = alloc(2048);
    int* RNGU = (int*)alloc(2048 * 28);
    float* WXI = alloc(224); float* WYI = alloc(224); float* IAI = alloc(4);
    int* RNGI = (int*)alloc(32);
    float* BIMAP = alloc(128 * 49);
    float* SIMAP = alloc(2048 * 49);
    float* OIMAP = alloc(2048 * 49);
    float* CTXP = alloc(Bimg * 256 * 49);
    bf16* OBJINT = (bf16*)alloc(1605632);        // [6272][512] bf16
    float* OBJF2 = alloc(1605632);               // [256][6272] fp32
    float* AS2 = alloc(1605632);                 // [256][6272]
    float* AO2 = alloc(1605632);                 // [256][6272]
    bf16* WOF16 = (bf16*)alloc(65536);           // [256][512]
    bf16* WRFXYZ16 = (bf16*)alloc(49152);        // [256][384]
    bf16* WRFC16 = (bf16*)alloc(1605632);        // [256][12544]
    bf16* WOFC16 = (bf16*)alloc(1605632);        // [256][12544]
    // region A: MBt (rel loop) | XOt (obj phase)  — disjoint lifetimes
    float* REGA = alloc(2408448);
    bf16* MBT = (bf16*)REGA;                     // [12544][384] bf16
    bf16* XOT = (bf16*)REGA;                     // [128][12544] bf16
    // region B: XBt+RPART+RT (rel loop) | OPART+OT (obj phase)
    float* REGB = alloc(1605632 + 28 * 256 * 256 + 256 * 256);
    bf16* XBT = (bf16*)REGB;                     // [256][12544] bf16
    float* RPART = REGB + 1605632;               // [28][256][256]
    float* RT = RPART + 28 * 256 * 256;          // [256][256]
    float* OPART = REGB;                         // [28][256][128]
    float* OT = REGB + 28 * 256 * 128;           // [128][256]

    // 1. weight concat + bf16 weight conversions
    catw_k<<<dim3((CCAT * Cch + 255) / 256), 256, 0, stream>>>(Wc, bc, Wr, br, WCAT, BCAT);
    f2b_k<<<dim3(512), 256, 0, stream>>>(Wof, WOF16, 131072);
    wrfxyz_k<<<dim3(384), 256, 0, stream>>>(Wrf, WRFXYZ16);
    f2b_k<<<dim3(12544), 256, 0, stream>>>(Wrfc, WRFC16, 3211264);
    f2b_k<<<dim3(12544), 256, 0, stream>>>(Wofc, WOFC16, 3211264);
    // 2. axis weights + 3. intersection maps
    axisw_k<<<dim3(2177), 64, 0, stream>>>(objects, WXO, WYO, IAO, RNGO,
                                           WXU, WYU, IAU, RNGU, WXI, WYI, IAI, RNGI);
    imap_k<<<dim3(128 + 2048), 64, 0, stream>>>(objects, BIMAP, SIMAP, OIMAP);
    // 4. ctx_all + rel_all (fp32 conv)
    gemm_k<<<dim3(16, 10, 8), 256, 0, stream>>>(WCAT, Cch, 0L, input, HW, (long)Cch * HW,
                                                CTXREL, HW, (long)CCAT * HW, BCAT,
                                                CCAT, HW, Cch);
    // 5-7. pooled operands (bf16, transposed)
    objpool_k<<<dim3(32, 16, 8), 256, 0, stream>>>(input, WXO, WYO, IAO, RNGO, OBJINT);
    ctxpool_k<<<dim3(32, 1, 8), 256, 0, stream>>>(CTXREL, WXI, WYI, IAI, RNGI, CTXP);
    objin_fill_k<<<dim3((8 * 256 * 784 + 255) / 256), 256, 0, stream>>>(CTXP, BIMAP, OBJINT);
    // 8. obj_feat = Wof @ obj_in + bof   (MFMA, M=256 N=6272 K=512)
    mfma_gemm_k<<<dim3(49, 2, 1), 256, 0, stream>>>(WOF16, 512, OBJINT, 512, 16, 1, 0,
                                                    OBJF2, 6272, 256, 6272, bof,
                                                    nullptr, nullptr, 0, nullptr);
    // 9/10. As, Ao (fp32 gemm, M=256 N=6272 K=256)
    gemm_k<<<dim3(98, 4, 1), 256, 0, stream>>>(Wrf, 896, 0L, OBJF2, 6272, 0L,
                                               AS2, 6272, 0L, nullptr, 256, 6272, 256);
    gemm_k<<<dim3(98, 4, 1), 256, 0, stream>>>(Wrf + 256, 896, 0L, OBJF2, 6272, 0L,
                                               AO2, 6272, 0L, nullptr, 256, 6272, 256);
    // 11. XOt pack
    xo_pack_k<<<dim3(49, 128), 256, 0, stream>>>(OBJF2, XOT);
    // 12. o-fc partials (MFMA split-K 28) + reduce + norm
    mfma_gemm_k<<<dim3(1, 2, 28), 256, 0, stream>>>(WOFC16, KFC, XOT, KFC, 392, 28, 2,
                                                    OPART, 128, 256, 128, nullptr,
                                                    nullptr, nullptr, 0, nullptr);
    reduce_bias_t_k<<<dim3((256 * 128 + 255) / 256), 256, 0, stream>>>(OPART, bofc, OT, 256, 128, 28);
    norm_store_k<<<dim3(128), 256, 0, stream>>>(OT, out, 0L);

    // per-image rel path
    for (int b = 0; b < Bimg; b++) {
        relpool_k<<<dim3(48, 256), 256, 0, stream>>>(CTXREL, WXU, WYU, IAU, RNGU,
                                                     SIMAP, OIMAP, MBT, b);
        // C1 fused: XBt = relu(Wrf_xyz @ MBt + brf + As[sub] + Ao[obj])
        mfma_gemm_k<<<dim3(98, 2, 1), 256, 0, stream>>>(WRFXYZ16, 384, MBT, 384, 12, 1, 1,
                                                        nullptr, 0, 256, KFC, brf,
                                                        AS2, AO2, b, XBT);
        // r-fc partials (MFMA split-K 28) + reduce + norm
        mfma_gemm_k<<<dim3(2, 2, 28), 256, 0, stream>>>(WRFC16, KFC, XBT, KFC, 392, 28, 2,
                                                        RPART, 256, 256, 256, nullptr,
                                                        nullptr, nullptr, 0, nullptr);
        reduce_bias_t_k<<<dim3((256 * 256 + 255) / 256), 256, 0, stream>>>(RPART, brfc, RT, 256, 256, 28);
        norm_store_k<<<dim3(256), 256, 0, stream>>>(RT, out, 32768L + (long)b * 65536L);
    }
}

// Round 3
// 1393.714 us; speedup vs baseline: 2.1363x; 1.1285x over previous
//
#include <hip/hip_runtime.h>
#include <hip/hip_bf16.h>

// SceneGraph head — Round 3.
// All GEMMs on bf16 MFMA. relpool restructured: 16 rois per channel-slab load
// (16x less staging), sT padded to stride 232 (kills 8-way bank conflicts).
// CTXREL layout: [ch 640][b 8][hw 1024] so conv is one MFMA GEMM (N=8192).

#define Bimg 8
#define Cch 256
#define HW 1024
#define CREL 384
#define CCAT 640
#define KFC 12544

typedef __hip_bfloat16 bf16;
typedef __attribute__((ext_vector_type(8))) short short8;
typedef __attribute__((ext_vector_type(4))) float f32x4;

__device__ __forceinline__ float hat_int(float t) {
    t = fminf(1.f, fmaxf(-1.f, t));
    return (t < 0.f) ? 0.5f * (t + 1.f) * (t + 1.f) : 1.f - 0.5f * (1.f - t) * (1.f - t);
}

// ---------------- weight prep ----------------
__global__ void catw_k(const float* __restrict__ Wc, const float* __restrict__ bc,
                       const float* __restrict__ Wr, const float* __restrict__ br,
                       bf16* __restrict__ Wcat, float* __restrict__ bcat) {
    int t = blockIdx.x * 256 + threadIdx.x;
    if (t < CCAT * Cch) {
        int d = t / Cch, c = t % Cch;
        Wcat[t] = __float2bfloat16((d < Cch) ? Wc[d * Cch + c] : Wr[(d - Cch) * Cch + c]);
    }
    if (t < CCAT) bcat[t] = (t < Cch) ? bc[t] : br[t - Cch];
}
__global__ void f2b_k(const float* __restrict__ s, bf16* __restrict__ d, int n) {
    int t = blockIdx.x * 256 + threadIdx.x;
    if (t < n) d[t] = __float2bfloat16(s[t]);
}
// Wrf cols [512:896) -> [256][384]
__global__ void wrfxyz_k(const float* __restrict__ Wrf, bf16* __restrict__ dst) {
    int t = blockIdx.x * 256 + threadIdx.x;
    if (t >= 256 * 384) return;
    int d = t / 384, k = t % 384;
    dst[t] = __float2bfloat16(Wrf[d * 896 + 512 + k]);
}
// Wrf cols [0:512) -> [512][256] (rows 0..255 = sub block, 256..511 = obj block)
__global__ void wasao_k(const float* __restrict__ Wrf, bf16* __restrict__ dst) {
    int t = blockIdx.x * 256 + threadIdx.x;
    if (t >= 512 * 256) return;
    int m = t >> 8, k = t & 255;
    dst[t] = __float2bfloat16((m < 256) ? Wrf[m * 896 + k] : Wrf[(m - 256) * 896 + 256 + k]);
}
// input [b][c][hw] fp32 -> INT [(b*1024+hw)][c] bf16 (LDS-tiled transpose)
__global__ __launch_bounds__(256) void int_t_k(const float* __restrict__ input, bf16* __restrict__ intp) {
    __shared__ float st[64][65];
    int hw0 = blockIdx.x * 64, c0 = blockIdx.y * 64, b = blockIdx.z;
    int tid = threadIdx.x;
#pragma unroll
    for (int i = 0; i < 16; i++) {
        int e = tid + i * 256;
        int c = e >> 6, hw = e & 63;
        st[c][hw] = input[(size_t)b * 262144 + (size_t)(c0 + c) * 1024 + hw0 + hw];
    }
    __syncthreads();
#pragma unroll
    for (int i = 0; i < 16; i++) {
        int e = tid + i * 256;
        int hw = e >> 6, c = e & 63;
        intp[((size_t)b * 1024 + hw0 + hw) * 256 + c0 + c] = __float2bfloat16(st[c][hw]);
    }
}

// ---------------- per-roi axis weights + support ranges + inv-area ----------------
__global__ void axisw_k(const float* __restrict__ objects,
                        float* wxo, float* wyo, float* iao, int* rngo,
                        float* wxu, float* wyu, float* iau, int* rngu,
                        float* wxi, float* wyi, float* iai, int* rngi) {
    int bid = blockIdx.x;
    float b0, b1, b2, b3;
    float *wx, *wy, *ia;
    int* rng;
    if (bid < 128) {
        b0 = objects[bid * 4]; b1 = objects[bid * 4 + 1];
        b2 = objects[bid * 4 + 2]; b3 = objects[bid * 4 + 3];
        wx = wxo + bid * 224; wy = wyo + bid * 224; ia = iao + bid; rng = rngo + bid * 28;
    } else if (bid < 128 + 2048) {
        int u = bid - 128;
        int img = u >> 8, pair = u & 255, i = pair >> 4, j = pair & 15;
        const float* sb = objects + (img * 16 + i) * 4;
        const float* ob = objects + (img * 16 + j) * 4;
        b0 = fminf(sb[0], ob[0]); b1 = fminf(sb[1], ob[1]);
        b2 = fmaxf(sb[2], ob[2]); b3 = fmaxf(sb[3], ob[3]);
        wx = wxu + u * 224; wy = wyu + u * 224; ia = iau + u; rng = rngu + u * 28;
    } else {
        b0 = 0.f; b1 = 0.f; b2 = 512.f; b3 = 512.f;
        wx = wxi; wy = wyi; ia = iai; rng = rngi;
    }
    const float sc = 0.0625f;
    int tid = threadIdx.x;
    {
        float lo = b0 * sc, hi = b2 * sc, bw = (hi - lo) * (1.f / 7.f);
        for (int e = tid; e < 224; e += 64) {
            int p = e / 32, i2 = e % 32;
            float st = lo + bw * p, en = st + bw;
            wx[e] = hat_int(en - (float)i2) - hat_int(st - (float)i2);
        }
        if (tid < 7) {
            float st = lo + bw * tid, en = st + bw;
            rng[tid] = max(0, (int)floorf(st) - 1);
            rng[7 + tid] = min(31, (int)ceilf(en) + 1);
        }
    }
    {
        float lo = b1 * sc, hi = b3 * sc, bw = (hi - lo) * (1.f / 7.f);
        for (int e = tid; e < 224; e += 64) {
            int p = e / 32, i2 = e % 32;
            float st = lo + bw * p, en = st + bw;
            wy[e] = hat_int(en - (float)i2) - hat_int(st - (float)i2);
        }
        if (tid < 7) {
            float st = lo + bw * tid, en = st + bw;
            rng[14 + tid] = max(0, (int)floorf(st) - 1);
            rng[21 + tid] = min(31, (int)ceilf(en) + 1);
        }
    }
    if (tid == 0) {
        float bwx = (b2 - b0) * sc * (1.f / 7.f), bwy = (b3 - b1) * sc * (1.f / 7.f);
        *ia = 1.f / fmaxf(bwx * bwy, 1e-8f);
    }
}

// ---------------- intersection maps ----------------
__global__ void imap_k(const float* __restrict__ objects,
                       float* __restrict__ bimap, float* __restrict__ simap,
                       float* __restrict__ oimap) {
    int bid = blockIdx.x;
    int tid = threadIdx.x;
    if (tid >= 49) return;
    int p = tid / 7, q = tid % 7;
    if (bid < 128) {
        float a0 = objects[bid * 4], a1 = objects[bid * 4 + 1];
        float a2 = objects[bid * 4 + 2], a3 = objects[bid * 4 + 3];
        float bw = 512.f / 7.f, bh = 512.f / 7.f;
        float gx0 = bw * q, gy0 = bh * p;
        float ox = fmaxf(fminf(gx0 + bw, a2) - fmaxf(gx0, a0), 0.f);
        float oy = fmaxf(fminf(gy0 + bh, a3) - fmaxf(gy0, a1), 0.f);
        bimap[bid * 49 + tid] = oy * ox / fmaxf(bw * bh, 1e-8f);
    } else {
        int u = bid - 128;
        int img = u >> 8, pair = u & 255, i = pair >> 4, j = pair & 15;
        const float* sb = objects + (img * 16 + i) * 4;
        const float* ob = objects + (img * 16 + j) * 4;
        float u0 = fminf(sb[0], ob[0]), u1 = fminf(sb[1], ob[1]);
        float u2 = fmaxf(sb[2], ob[2]), u3 = fmaxf(sb[3], ob[3]);
        float bw = (u2 - u0) / 7.f, bh = (u3 - u1) / 7.f;
        float gx0 = u0 + bw * q, gy0 = u1 + bh * p;
        float inv = 1.f / fmaxf(bw * bh, 1e-8f);
        float oxs = fmaxf(fminf(gx0 + bw, sb[2]) - fmaxf(gx0, sb[0]), 0.f);
        float oys = fmaxf(fminf(gy0 + bh, sb[3]) - fmaxf(gy0, sb[1]), 0.f);
        simap[u * 49 + tid] = oys * oxs * inv;
        float oxo = fmaxf(fminf(gx0 + bw, ob[2]) - fmaxf(gx0, ob[0]), 0.f);
        float oyo = fmaxf(fminf(gy0 + bh, ob[3]) - fmaxf(gy0, ob[1]), 0.f);
        oimap[u * 49 + tid] = oyo * oxo * inv;
    }
}

// ---------------- bf16 MFMA GEMM: C[m,n] = sum_k A[m,k] * BT[n,k] ----------------
// 128x128 tile, BK=32, 256 threads. M,N multiples of 128, K of 32.
// mode 0: Cf[m*ldc+n] = acc (+bias[m])
// mode 1: rel fused epilogue -> Ct bf16 = relu(acc + bias + AS + AO), pair-major
// mode 2: split-K partials Cf[kz][Mtot][Ntot]
// mode 3: Ct[n*ldct+m] = bf16(acc + bias[m])   (transposed bf16 out)
__global__ __launch_bounds__(256) void mfma_gemm_k(
    const bf16* __restrict__ A, int lda,
    const bf16* __restrict__ BT, int ldbt,
    int Ktiles, int splitk, int mode,
    float* __restrict__ Cf, int ldc, int Mtot, int Ntot,
    const float* __restrict__ bias,
    const float* __restrict__ AS2, const float* __restrict__ AO2, int bimg,
    bf16* __restrict__ Ct, int ldct) {
    __shared__ short sA[128 * 40];
    __shared__ short sB[128 * 40];
    const int tid = threadIdx.x;
    const int m0 = blockIdx.y * 128, n0 = blockIdx.x * 128;
    const int kz = blockIdx.z;
    const int tp = (Ktiles + splitk - 1) / splitk;
    const int kt0 = kz * tp;
    const int kt1 = min(Ktiles, kt0 + tp);
    const int srow = tid >> 2, scol = (tid & 3) * 8;
    const int lane = tid & 63, wid = tid >> 6;
    const int wm = (wid >> 1) * 64, wn = (wid & 1) * 64;
    const int lrow = lane & 15, lk = (lane >> 4) * 8;
    f32x4 acc[4][4];
#pragma unroll
    for (int i = 0; i < 4; i++)
#pragma unroll
        for (int j = 0; j < 4; j++) acc[i][j] = (f32x4){0.f, 0.f, 0.f, 0.f};
    const bf16* gA = A + (size_t)(m0 + srow) * lda + scol;
    const bf16* gB = BT + (size_t)(n0 + srow) * ldbt + scol;
    for (int kt = kt0; kt < kt1; kt++) {
        short8 a0 = *(const short8*)(gA + (size_t)kt * 32);
        short8 a1 = *(const short8*)(gA + (size_t)64 * lda + (size_t)kt * 32);
        short8 b0 = *(const short8*)(gB + (size_t)kt * 32);
        short8 b1 = *(const short8*)(gB + (size_t)64 * ldbt + (size_t)kt * 32);
        __syncthreads();
        *(short8*)&sA[srow * 40 + scol] = a0;
        *(short8*)&sA[(srow + 64) * 40 + scol] = a1;
        *(short8*)&sB[srow * 40 + scol] = b0;
        *(short8*)&sB[(srow + 64) * 40 + scol] = b1;
        __syncthreads();
        short8 af[4], bfr[4];
#pragma unroll
        for (int f = 0; f < 4; f++) {
            af[f] = *(const short8*)&sA[(wm + f * 16 + lrow) * 40 + lk];
            bfr[f] = *(const short8*)&sB[(wn + f * 16 + lrow) * 40 + lk];
        }
#pragma unroll
        for (int i = 0; i < 4; i++)
#pragma unroll
            for (int j = 0; j < 4; j++)
                acc[i][j] = __builtin_amdgcn_mfma_f32_16x16x32_bf16(af[i], bfr[j], acc[i][j], 0, 0, 0);
    }
    const int rbase = (lane >> 4) * 4, cf = lane & 15;
    if (mode == 2) {
        float* P = Cf + (size_t)kz * Mtot * Ntot;
#pragma unroll
        for (int i = 0; i < 4; i++)
#pragma unroll
            for (int reg = 0; reg < 4; reg++) {
                int m = m0 + wm + i * 16 + rbase + reg;
#pragma unroll
                for (int j = 0; j < 4; j++) {
                    int n = n0 + wn + j * 16 + cf;
                    P[(size_t)m * Ntot + n] = acc[i][j][reg];
                }
            }
    } else if (mode == 0) {
#pragma unroll
        for (int i = 0; i < 4; i++)
#pragma unroll
            for (int reg = 0; reg < 4; reg++) {
                int m = m0 + wm + i * 16 + rbase + reg;
                float bv = bias ? bias[m] : 0.f;
#pragma unroll
                for (int j = 0; j < 4; j++) {
                    int n = n0 + wn + j * 16 + cf;
                    Cf[(size_t)m * ldc + n] = acc[i][j][reg] + bv;
                }
            }
    } else if (mode == 3) {
#pragma unroll
        for (int i = 0; i < 4; i++)
#pragma unroll
            for (int reg = 0; reg < 4; reg++) {
                int m = m0 + wm + i * 16 + rbase + reg;
                float bv = bias ? bias[m] : 0.f;
#pragma unroll
                for (int j = 0; j < 4; j++) {
                    int n = n0 + wn + j * 16 + cf;
                    Ct[(size_t)n * ldct + m] = __float2bfloat16(acc[i][j][reg] + bv);
                }
            }
    } else {  // mode 1
#pragma unroll
        for (int i = 0; i < 4; i++)
#pragma unroll
            for (int reg = 0; reg < 4; reg++) {
                int m = m0 + wm + i * 16 + rbase + reg;
                float bv = bias[m];
#pragma unroll
                for (int j = 0; j < 4; j++) {
                    int n = n0 + wn + j * 16 + cf;
                    int r = n / 49;
                    int pq = n - r * 49;
                    int ii = r >> 4, jj = r & 15;
                    float v = acc[i][j][reg] + bv
                            + AS2[(size_t)m * 6272 + bimg * 784 + ii * 49 + pq]
                            + AO2[(size_t)m * 6272 + bimg * 784 + jj * 49 + pq];
                    Ct[(size_t)r * KFC + m * 49 + pq] = __float2bfloat16(fmaxf(v, 0.f));
                }
            }
    }
}

// ---------------- obj pooling: input -> OBJINT ch [0,256), 16 rois per slab ----------------
__global__ __launch_bounds__(256) void objpool_k(
    const float* __restrict__ input,
    const float* __restrict__ wxo, const float* __restrict__ wyo,
    const float* __restrict__ iao, const int* __restrict__ rngo,
    bf16* __restrict__ objint) {
    int cg = blockIdx.x;   // 0..31
    int b = blockIdx.y;    // 0..7
    __shared__ float sF[8192];
    __shared__ float sT[8 * 232];
    __shared__ float sWx[224], sWy[224];
    __shared__ int rng[28];
    int tid = threadIdx.x;
    const float* feat = input + (size_t)b * (Cch * HW) + (size_t)cg * 8 * HW;
    for (int e = tid; e < 8192; e += 256) sF[e] = feat[e];
    for (int r = 0; r < 16; r++) {
        int rid = b * 16 + r;
        __syncthreads();
        if (tid < 224) { sWx[tid] = wxo[rid * 224 + tid]; sWy[tid] = wyo[rid * 224 + tid]; }
        int t2 = tid - 224;
        if (t2 >= 0 && t2 < 28) rng[t2] = rngo[rid * 28 + t2];
        __syncthreads();
        for (int e = tid; e < 1792; e += 256) {
            int c = e / 224, rem = e - c * 224, p = rem >> 5, wc = rem & 31;
            int h0 = rng[14 + p], h1 = rng[21 + p];
            float s = 0.f;
            for (int h = h0; h <= h1; h++) s += sF[c * 1024 + h * 32 + wc] * sWy[p * 32 + h];
            sT[c * 232 + rem] = s;
        }
        __syncthreads();
        float ia = iao[rid];
        for (int e = tid; e < 392; e += 256) {
            int pq = e >> 3, c = e & 7, p = pq / 7, q = pq - p * 7;
            int w0 = rng[q], w1 = rng[7 + q];
            float s = 0.f;
            for (int wv = w0; wv <= w1; wv++) s += sT[c * 232 + p * 32 + wv] * sWx[q * 32 + wv];
            objint[((size_t)b * 784 + r * 49 + pq) * 512 + cg * 8 + c] = __float2bfloat16(s * ia);
        }
    }
}

// ---------------- ctx pooling: CTXREL[ch][b][hw] ch<256, img box -> ctxp fp32 ----------------
__global__ __launch_bounds__(256) void ctxpool_k(
    const float* __restrict__ ctxrel,
    const float* __restrict__ wxi, const float* __restrict__ wyi,
    const float* __restrict__ iai, const int* __restrict__ rngi,
    float* __restrict__ ctxp) {
    int cg = blockIdx.x;   // 0..31
    int b = blockIdx.y;    // 0..7
    __shared__ float sF[8192];
    __shared__ float sT[8 * 232];
    __shared__ float sWx[224], sWy[224];
    __shared__ int rng[28];
    int tid = threadIdx.x;
    for (int e = tid; e < 8192; e += 256)
        sF[e] = ctxrel[(size_t)(cg * 8 + (e >> 10)) * 8192 + b * 1024 + (e & 1023)];
    if (tid < 224) { sWx[tid] = wxi[tid]; sWy[tid] = wyi[tid]; }
    int t2 = tid - 224;
    if (t2 >= 0 && t2 < 28) rng[t2] = rngi[t2];
    __syncthreads();
    for (int e = tid; e < 1792; e += 256) {
        int c = e / 224, rem = e - c * 224, p = rem >> 5, wc = rem & 31;
        int h0 = rng[14 + p], h1 = rng[21 + p];
        float s = 0.f;
        for (int h = h0; h <= h1; h++) s += sF[c * 1024 + h * 32 + wc] * sWy[p * 32 + h];
        sT[c * 232 + rem] = s;
    }
    __syncthreads();
    float ia = iai[0];
    for (int e = tid; e < 392; e += 256) {
        int pq = e >> 3, c = e & 7, p = pq / 7, q = pq - p * 7;
        int w0 = rng[q], w1 = rng[7 + q];
        float s = 0.f;
        for (int wv = w0; wv <= w1; wv++) s += sT[c * 232 + p * 32 + wv] * sWx[q * 32 + wv];
        ctxp[(size_t)b * 12544 + (cg * 8 + c) * 49 + pq] = s * ia;
    }
}

// ---------------- rel pooling: 16 rois per slab, imap-scaled -> MBt bf16 ----------------
__global__ __launch_bounds__(256) void relpool_k(
    const float* __restrict__ ctxrel,
    const float* __restrict__ wxu, const float* __restrict__ wyu,
    const float* __restrict__ iau, const int* __restrict__ rngu,
    const float* __restrict__ simap, const float* __restrict__ oimap,
    bf16* __restrict__ mbt, int b) {
    int cg = blockIdx.x;   // 0..47
    int rg = blockIdx.y;   // 0..15
    __shared__ float sF[8192];
    __shared__ float sT[8 * 232];
    __shared__ float sWx[224], sWy[224];
    __shared__ float sSI[49], sOI[49];
    __shared__ int rng[28];
    int tid = threadIdx.x;
    for (int e = tid; e < 8192; e += 256)
        sF[e] = ctxrel[(size_t)(256 + cg * 8 + (e >> 10)) * 8192 + b * 1024 + (e & 1023)];
    int cglob0 = cg * 8;
    for (int r2 = 0; r2 < 16; r2++) {
        int r = rg * 16 + r2;
        int rid = b * 256 + r;
        __syncthreads();
        if (tid < 224) { sWx[tid] = wxu[rid * 224 + tid]; sWy[tid] = wyu[rid * 224 + tid]; }
        int t2 = tid - 224;
        if (t2 >= 0 && t2 < 28) rng[t2] = rngu[rid * 28 + t2];
        if (tid < 49) sSI[tid] = simap[rid * 49 + tid];
        else if (tid < 98) sOI[tid - 49] = oimap[rid * 49 + tid - 49];
        __syncthreads();
        for (int e = tid; e < 1792; e += 256) {
            int c = e / 224, rem = e - c * 224, p = rem >> 5, wc = rem & 31;
            int h0 = rng[14 + p], h1 = rng[21 + p];
            float s = 0.f;
            for (int h = h0; h <= h1; h++) s += sF[c * 1024 + h * 32 + wc] * sWy[p * 32 + h];
            sT[c * 232 + rem] = s;
        }
        __syncthreads();
        float ia = iau[rid];
        for (int e = tid; e < 392; e += 256) {
            int pq = e >> 3, c = e & 7, p = pq / 7, q = pq - p * 7;
            int w0 = rng[q], w1 = rng[7 + q];
            float s = 0.f;
            for (int wv = w0; wv <= w1; wv++) s += sT[c * 232 + p * 32 + wv] * sWx[q * 32 + wv];
            s *= ia;
            int cglob = cglob0 + c;
            if (cglob >= 128 && cglob < 256) s *= sSI[pq];
            else if (cglob >= 256) s *= sOI[pq];
            mbt[((size_t)r * 49 + pq) * 384 + cglob] = __float2bfloat16(s);
        }
    }
}

// ---------------- OBJINT ch [256,512): x_c broadcast + y_c * box_imap ----------------
__global__ void objin_fill_k(const float* __restrict__ ctxp, const float* __restrict__ bimap,
                             bf16* __restrict__ objint) {
    int t = blockIdx.x * 256 + threadIdx.x;
    if (t >= 8 * 784 * 256) return;
    int b = t / 200704;
    int rem = t - b * 200704;
    int col = rem >> 8, j = rem & 255;
    int r = col / 49, pq = col - r * 49;
    float v = ctxp[(size_t)b * 12544 + j * 49 + pq];
    if (j >= 128) v *= bimap[(b * 16 + r) * 49 + pq];
    objint[((size_t)b * 784 + col) * 512 + 256 + j] = __float2bfloat16(v);
}

// ---------------- XOt[col][k] = relu(OBJFT) ----------------
__global__ void xo_pack_k(const bf16* __restrict__ objft, bf16* __restrict__ xot) {
    int col = blockIdx.y;                       // 0..127 (b*16+i)
    int k = blockIdx.x * 256 + threadIdx.x;     // 0..12543 (d*49+pq)
    int d = k / 49, pq = k - d * 49;
    int b = col >> 4, i = col & 15;
    float v = __bfloat162float(objft[((size_t)b * 784 + i * 49 + pq) * 256 + d]);
    xot[(size_t)col * KFC + k] = __float2bfloat16(fmaxf(v, 0.f));
}

// ---------------- reduce split-K partials + bias, transposed [n][m] ----------------
__global__ void reduce_bias_t_k(const float* __restrict__ Pd, const float* __restrict__ bias,
                                float* __restrict__ outT, int M, int N, int splitk) {
    int t = blockIdx.x * 256 + threadIdx.x;
    if (t >= M * N) return;
    int nn = t / M, m = t - nn * M;
    float s = bias[m];
    for (int z = 0; z < splitk; z++) s += Pd[(size_t)z * M * N + (size_t)m * N + nn];
    outT[t] = s;
}

// ---------------- L2 normalize 256-vectors ----------------
__global__ void norm_store_k(const float* __restrict__ inT, float* __restrict__ out, long outBase) {
    int vec = blockIdx.x, tid = threadIdx.x;
    float v = inT[(size_t)vec * 256 + tid];
    float s = v * v;
    for (int o = 32; o > 0; o >>= 1) s += __shfl_down(s, o, 64);
    __shared__ float red[4];
    if ((tid & 63) == 0) red[tid >> 6] = s;
    __syncthreads();
    float tot = red[0] + red[1] + red[2] + red[3];
    out[outBase + (size_t)vec * 256 + tid] = v / sqrtf(tot);
}

extern "C" void kernel_launch(void* const* d_in, const int* in_sizes, int n_in,
                              void* d_out, int out_size, void* d_ws, size_t ws_size,
                              hipStream_t stream) {
    const float* input = (const float*)d_in[0];
    const float* objects = (const float*)d_in[1];
    const float* Wc = (const float*)d_in[3];
    const float* bc = (const float*)d_in[4];
    const float* Wr = (const float*)d_in[5];
    const float* br = (const float*)d_in[6];
    const float* Wof = (const float*)d_in[7];
    const float* bof = (const float*)d_in[8];
    const float* Wrf = (const float*)d_in[9];
    const float* brf = (const float*)d_in[10];
    const float* Wofc = (const float*)d_in[11];
    const float* bofc = (const float*)d_in[12];
    const float* Wrfc = (const float*)d_in[13];
    const float* brfc = (const float*)d_in[14];
    float* out = (float*)d_out;

    float* w = (float*)d_ws;
    size_t off = 0;
    auto alloc = [&](size_t nf) { nf = (nf + 3) & ~(size_t)3; float* p = w + off; off += nf; return p; };
    bf16* WCAT16 = (bf16*)alloc(81920);          // [640][256]
    float* BCAT = alloc(CCAT);
    float* CTXREL = alloc((size_t)CCAT * 8192);  // [640][8][1024] fp32
    bf16* INT16 = (bf16*)alloc(1048576);         // [8192][256]
    float* WXO = alloc(128 * 224); float* WYO = alloc(128 * 224); float* IAO = alloc(128);
    int* RNGO = (int*)alloc(128 * 28);
    float* WXU = alloc(2048 * 224); float* WYU = alloc(2048 * 224); float* IAU = alloc(2048);
    int* RNGU = (int*)alloc(2048 * 28);
    float* WXI = alloc(224); float* WYI = alloc(224); float* IAI = alloc(4);
    int* RNGI = (int*)alloc(32);
    float* BIMAP = alloc(128 * 49);
    float* SIMAP = alloc(2048 * 49);
    float* OIMAP = alloc(2048 * 49);
    float* CTXP = alloc(Bimg * 256 * 49);
    bf16* OBJINT = (bf16*)alloc(1605632);        // [6272][512]
    bf16* OBJFT = (bf16*)alloc(802816);          // [6272][256]
    float* AS2AO2 = alloc((size_t)512 * 6272);   // rows 0..255 = As, 256..511 = Ao
    bf16* WOF16 = (bf16*)alloc(65536);           // [256][512]
    bf16* WASAO16 = (bf16*)alloc(65536);         // [512][256]
    bf16* WRFXYZ16 = (bf16*)alloc(49152);        // [256][384]
    bf16* WRFC16 = (bf16*)alloc(1605632);        // [256][12544]
    bf16* WOFC16 = (bf16*)alloc(1605632);        // [256][12544]
    // region A: MBt (rel loop) | XOt (obj phase)
    float* REGA = alloc(2408448);
    bf16* MBT = (bf16*)REGA;                     // [12544][384]
    bf16* XOT = (bf16*)REGA;                     // [128][12544]
    // region B: XBt+RPART+RT (rel) | OPART+OT (obj)
    float* REGB = alloc(1605632 + 49 * 65536 + 65536);
    bf16* XBT = (bf16*)REGB;                     // [256][12544]
    float* RPART = REGB + 1605632;               // [49][256][256]
    float* RT = RPART + 49 * 65536;              // [256][256]
    float* OPART = REGB;                         // [49][256][128]
    float* OT = REGB + 49 * 32768;               // [128][256]

    // weight prep
    catw_k<<<dim3((CCAT * Cch + 255) / 256), 256, 0, stream>>>(Wc, bc, Wr, br, WCAT16, BCAT);
    f2b_k<<<dim3(512), 256, 0, stream>>>(Wof, WOF16, 131072);
    wasao_k<<<dim3(512), 256, 0, stream>>>(Wrf, WASAO16);
    wrfxyz_k<<<dim3(384), 256, 0, stream>>>(Wrf, WRFXYZ16);
    f2b_k<<<dim3(12544), 256, 0, stream>>>(Wrfc, WRFC16, 3211264);
    f2b_k<<<dim3(12544), 256, 0, stream>>>(Wofc, WOFC16, 3211264);
    // geometry
    axisw_k<<<dim3(2177), 64, 0, stream>>>(objects, WXO, WYO, IAO, RNGO,
                                           WXU, WYU, IAU, RNGU, WXI, WYI, IAI, RNGI);
    imap_k<<<dim3(128 + 2048), 64, 0, stream>>>(objects, BIMAP, SIMAP, OIMAP);
    // input transpose + conv (one MFMA GEMM: M=640, N=8192, K=256)
    int_t_k<<<dim3(16, 4, 8), 256, 0, stream>>>(input, INT16);
    mfma_gemm_k<<<dim3(64, 5, 1), 256, 0, stream>>>(WCAT16, 256, INT16, 256, 8, 1, 0,
                                                    CTXREL, 8192, 640, 8192, BCAT,
                                                    nullptr, nullptr, 0, nullptr, 0);
    // pooled operands
    objpool_k<<<dim3(32, 8), 256, 0, stream>>>(input, WXO, WYO, IAO, RNGO, OBJINT);
    ctxpool_k<<<dim3(32, 8), 256, 0, stream>>>(CTXREL, WXI, WYI, IAI, RNGI, CTXP);
    objin_fill_k<<<dim3((8 * 784 * 256 + 255) / 256), 256, 0, stream>>>(CTXP, BIMAP, OBJINT);
    // obj_feat = Wof @ obj_in + bof -> bf16 transposed [6272][256]
    mfma_gemm_k<<<dim3(49, 2, 1), 256, 0, stream>>>(WOF16, 512, OBJINT, 512, 16, 1, 3,
                                                    nullptr, 0, 256, 6272, bof,
                                                    nullptr, nullptr, 0, OBJFT, 256);
    // As;Ao = Wrf[:, :512] @ obj_feat  (M=512, N=6272, K=256)
    mfma_gemm_k<<<dim3(49, 4, 1), 256, 0, stream>>>(WASAO16, 256, OBJFT, 256, 8, 1, 0,
                                                    AS2AO2, 6272, 512, 6272, nullptr,
                                                    nullptr, nullptr, 0, nullptr, 0);
    // o-fc
    xo_pack_k<<<dim3(49, 128), 256, 0, stream>>>(OBJFT, XOT);
    mfma_gemm_k<<<dim3(1, 2, 49), 256, 0, stream>>>(WOFC16, KFC, XOT, KFC, 392, 49, 2,
                                                    OPART, 128, 256, 128, nullptr,
                                                    nullptr, nullptr, 0, nullptr, 0);
    reduce_bias_t_k<<<dim3((256 * 128 + 255) / 256), 256, 0, stream>>>(OPART, bofc, OT, 256, 128, 49);
    norm_store_k<<<dim3(128), 256, 0, stream>>>(OT, out, 0L);

    // per-image rel path
    for (int b = 0; b < Bimg; b++) {
        relpool_k<<<dim3(48, 16), 256, 0, stream>>>(CTXREL, WXU, WYU, IAU, RNGU,
                                                    SIMAP, OIMAP, MBT, b);
        mfma_gemm_k<<<dim3(98, 2, 1), 256, 0, stream>>>(WRFXYZ16, 384, MBT, 384, 12, 1, 1,
                                                        nullptr, 0, 256, KFC, brf,
                                                        AS2AO2, AS2AO2 + (size_t)256 * 6272, b, XBT, 0);
        mfma_gemm_k<<<dim3(2, 2, 49), 256, 0, stream>>>(WRFC16, KFC, XBT, KFC, 392, 49, 2,
                                                        RPART, 256, 256, 256, nullptr,
                                                        nullptr, nullptr, 0, nullptr, 0);
        reduce_bias_t_k<<<dim3((256 * 256 + 255) / 256), 256, 0, stream>>>(RPART, brfc, RT, 256, 256, 49);
        norm_store_k<<<dim3(256), 256, 0, stream>>>(RT, out, 32768L + (long)b * 65536L);
    }
}